// Round 6
// baseline (4411.136 us; speedup 1.0000x reference)
//
#include <hip/hip_runtime.h>
#include <hip/hip_bf16.h>

// ---------------------------------------------------------------------------
// RNNModel (MDN-RNN): embed+concat -> x_pre -> 511-step LSTM -> out GEMM ->
// logsumexp heads.
//   lstm_k: persistent 128 blocks (1/CU), each owns 8 h-cols = 32 gate rows.
//     W_hh slice bf16 in LDS (64 KB). Per step MFMA [32 x 32gates x K1152].
//     NEW (R6): cross-block h exchange is SELF-VALIDATING TAGGED DATA --
//     each h value ships as u32 = bf16<<16 | step_tag, 2 per u64, relaxed
//     agent-scope 8B atomics. Readers poll the u64s they consume until tags
//     match t. No flags, no vmcnt drain, no arrival barrier: collapses the
//     R4/R5 4-LLC-round-trip chain (store+drain+flag+detect) to ~1.5 trips.
//     Per-wave K-step kk waits only on writer blocks 4*(8w+kk)..+4.
//     Replay safety: both h32 phases memset each launch (tag 0 == valid h0);
//     in-run phases hold disjoint tag parities, so no false matches.
//   hs3: [128 regions][16384 rows][16B] per-block contiguous; out_gemm
//     A-frag = single 16B load. wout16 overlaps h32 (converted AFTER lstm).
// ---------------------------------------------------------------------------

typedef float f4 __attribute__((ext_vector_type(4)));
typedef short s8 __attribute__((ext_vector_type(8)));
typedef unsigned short us8v __attribute__((ext_vector_type(8)));
typedef unsigned short us4v __attribute__((ext_vector_type(4)));
typedef unsigned long long u64;
typedef unsigned u32;

#define DEV __device__ __forceinline__

DEV unsigned short f2b(float f) {          // fp32 -> bf16 RNE
  unsigned u = __float_as_uint(f);
  return (unsigned short)((u + 0x7FFFu + ((u >> 16) & 1u)) >> 16);
}
DEV float b2f(unsigned short s) { return __uint_as_float(((unsigned)s) << 16); }

DEV f4 MFMA(s8 a, s8 b, f4 c) {
  return __builtin_amdgcn_mfma_f32_16x16x32_bf16(a, b, c, 0, 0, 0);
}
DEV s8 LD8(const unsigned short* p) { return *reinterpret_cast<const s8*>(p); }

DEV u64 AL(const u64* p) {
  return __hip_atomic_load(p, __ATOMIC_RELAXED, __HIP_MEMORY_SCOPE_AGENT);
}
DEV bool TOK(u64 q, u32 tgt) {   // both 16-bit tags match target step
  return (((u32)q & 0xFFFFu) == tgt) & (((u32)(q >> 32) & 0xFFFFu) == tgt);
}
DEV u32 PK(u64 q) {              // strip tags: 2 bf16 packed in one u32
  return (((u32)(q >> 16)) & 0xFFFFu) | (((u32)(q >> 32)) & 0xFFFF0000u);
}

DEV float sigf(float x) {   // 1/(1+e^-x) via v_exp + v_rcp (~1e-6 rel)
  float e = __builtin_amdgcn_exp2f(x * -1.44269504f);
  return __builtin_amdgcn_rcpf(1.f + e);
}
DEV float tanhf_fast(float x) {  // 1 - 2/(e^{2x}+1); saturates correctly
  float e = __builtin_amdgcn_exp2f(x * 2.88539008f);
  return 1.f - 2.f * __builtin_amdgcn_rcpf(e + 1.f);
}

// ---- workspace layout (bytes) ----
// [0,2048)          spare
// [2048, +262144)   h32: 2 phases x 32 batch x 512 u64 (tagged h) ...
//                   ... UNION wout16 [2048, +3934208) (written after lstm_k)
// [3936256, +4MiB)  zt : 512 x 32 x 128 bf16
// [8130560, +32MiB) hs3: 128 regions x 16384 rows x 16B
static constexpr size_t WS_H32  = 2048;
static constexpr size_t WS_WOUT = 2048;
static constexpr size_t WS_ZT   = 3936256;
static constexpr size_t WS_HS3  = 8130560;
static constexpr size_t WS_END  = 41684992;

// ---------------------------------------------------------------------------
__global__ void cvt_wout_k(const float* __restrict__ W, unsigned short* __restrict__ o) {
  int i = blockIdx.x * 256 + threadIdx.x;         // 491776 float4 units exact
  if (i < 491776) {
    const float4 v = reinterpret_cast<const float4*>(W)[i];
    us4v u; u[0] = f2b(v.x); u[1] = f2b(v.y); u[2] = f2b(v.z); u[3] = f2b(v.w);
    reinterpret_cast<us4v*>(o)[i] = u;
  }
}

__global__ void cvt_z_k(const float* __restrict__ z, unsigned short* __restrict__ zt) {
  int u = blockIdx.x * 256 + threadIdx.x;         // 524288 units exact
  if (u < 524288) {
    int d4 = u & 31, bt = u >> 5;
    int b = bt & 31, t = bt >> 5;
    const float4 v = reinterpret_cast<const float4*>(z)[(b * 512 + t) * 32 + d4];
    us4v uu; uu[0] = f2b(v.x); uu[1] = f2b(v.y); uu[2] = f2b(v.z); uu[3] = f2b(v.w);
    reinterpret_cast<us4v*>(zt)[u] = uu;
  }
}

__global__ void zero_hs_tail_k(u64* __restrict__ hs3u) {
  // rows 16352..16383 (32 rows x 2 u64) of all 128 regions = 8192 u64
  int i = blockIdx.x * 256 + threadIdx.x;
  if (i < 8192) {
    int reg = i >> 6, rr = (i >> 1) & 31, hf = i & 1;
    hs3u[(size_t)reg * 32768 + (size_t)(16352 + rr) * 2 + hf] = 0ull;
  }
}

// ---------------------------------------------------------------------------
// Persistent LSTM. grid=128, block=256 (4 waves). Block blk owns h cols
// [8blk,8blk+8) = 32 gate rows {type*1024 + 8blk + q}. Wave w owns K-slice
// [256w,+256) of W_hh + z-K [32w,+32). 511 steps, tagged-h self-sync.
__global__ __launch_bounds__(256, 1) void lstm_k(
    const float* __restrict__ Whh, const float* __restrict__ Wih,
    const float* __restrict__ embed, const float* __restrict__ bih,
    const float* __restrict__ bhh, const int* __restrict__ actions,
    const int* __restrict__ dones, const unsigned short* __restrict__ zt,
    u64* __restrict__ h32, u64* __restrict__ hs3u) {
  const int blk = blockIdx.x;
  const int tid = threadIdx.x;
  const int lane = tid & 63;
  const int w = tid >> 6;
  const int ln = lane & 15, lk = lane >> 4;

  __shared__ alignas(16) unsigned short whh_sw[32768];   // [kt32][nt2][64][8] 64 KB
  __shared__ alignas(16) unsigned short wz_sw[4096];     // [kz4][nt2][64][8]   8 KB
  __shared__ float abias[18][32];
  __shared__ float red[4][32][34];     // stride 34: write 2-way, read <=4-way
  __shared__ alignas(16) unsigned short st[32][8];   // unmasked h staging -> hs3

  for (int i = tid; i < 32768; i += 256) {
    int j = i & 7, L = (i >> 3) & 63, nt = (i >> 9) & 1, kt = i >> 10;
    int n = nt * 16 + (L & 15);
    int grow = (n >> 3) * 1024 + blk * 8 + (n & 7);
    int k = kt * 32 + ((L >> 4) << 3) + j;
    whh_sw[i] = f2b(Whh[grow * 1024 + k]);
  }
  for (int i = tid; i < 4096; i += 256) {
    int j = i & 7, L = (i >> 3) & 63, nt = (i >> 9) & 1, kz = i >> 10;
    int n = nt * 16 + (L & 15);
    int grow = (n >> 3) * 1024 + blk * 8 + (n & 7);
    int k = kz * 32 + ((L >> 4) << 3) + j;
    wz_sw[i] = f2b(Wih[grow * 144 + k]);
  }
  for (int i = tid; i < 576; i += 256) {
    int a = i >> 5, n = i & 31;
    int grow = (n >> 3) * 1024 + blk * 8 + (n & 7);
    float s = bih[grow] + bhh[grow];
    for (int j = 0; j < 16; ++j) s += embed[a * 16 + j] * Wih[grow * 144 + 128 + j];
    abias[a][n] = s;
  }
  __syncthreads();

  const int eb = tid >> 3, eq = tid & 7;   // epilogue: thread -> (batch, col)
  float c_state = 0.f;

  for (int t = 0; t < 511; ++t) {
    const u64* hb = h32 + (size_t)(t & 1) * 16384;   // phase: [32][512] u64

    f4 acc00 = {0.f,0.f,0.f,0.f}, acc01 = {0.f,0.f,0.f,0.f};
    f4 acc10 = {0.f,0.f,0.f,0.f}, acc11 = {0.f,0.f,0.f,0.f};

    {  // z contribution: independent of h, issue first
      const unsigned short* zb = zt + (size_t)t * 4096;
      const int kz = w * 32 + (lk << 3);
      s8 a0 = LD8(zb + ln * 128 + kz);
      s8 a1 = LD8(zb + (ln + 16) * 128 + kz);
      s8 b0 = LD8(wz_sw + (((w << 1) + 0) * 64 + lane) * 8);
      s8 b1 = LD8(wz_sw + (((w << 1) + 1) * 64 + lane) * 8);
      acc00 = MFMA(a0, b0, acc00);  acc01 = MFMA(a0, b1, acc01);
      acc10 = MFMA(a1, b0, acc10);  acc11 = MFMA(a1, b1, acc11);
    }
    const int a_t = actions[eb * 512 + t];
    const float m_t = 1.f - (float)dones[eb * 512 + t];
    const u32 tgt = (u32)t;          // tag expected in phase t&1

#pragma unroll
    for (int kk = 0; kk < 8; ++kk) {   // this wave's 8 K-steps of W_hh
      const int kt = w * 8 + kk;
      const int c2 = kt * 16 + (lk << 2);           // u64 col base
      const u64* pA = hb + ln * 512 + c2;
      const u64* pB = pA + 8192;                    // (ln+16)*512
      u64 qa0, qa1, qa2, qa3, qb0, qb1, qb2, qb3;
      unsigned spin = 0;
      for (;;) {   // poll the exact data consumed: waits only on 4 writers
        qa0 = AL(pA + 0); qa1 = AL(pA + 1); qa2 = AL(pA + 2); qa3 = AL(pA + 3);
        qb0 = AL(pB + 0); qb1 = AL(pB + 1); qb2 = AL(pB + 2); qb3 = AL(pB + 3);
        bool ok = TOK(qa0, tgt) & TOK(qa1, tgt) & TOK(qa2, tgt) & TOK(qa3, tgt) &
                  TOK(qb0, tgt) & TOK(qb1, tgt) & TOK(qb2, tgt) & TOK(qb3, tgt);
        if (__all(ok) || ++spin > 8192) break;
        __builtin_amdgcn_s_sleep(1);
      }
      union { u32 u[4]; s8 v; } fa, fb;
      fa.u[0] = PK(qa0); fa.u[1] = PK(qa1); fa.u[2] = PK(qa2); fa.u[3] = PK(qa3);
      fb.u[0] = PK(qb0); fb.u[1] = PK(qb1); fb.u[2] = PK(qb2); fb.u[3] = PK(qb3);
      s8 b0 = LD8(whh_sw + (((kt << 1) + 0) * 64 + lane) * 8);
      s8 b1 = LD8(whh_sw + (((kt << 1) + 1) * 64 + lane) * 8);
      acc00 = MFMA(fa.v, b0, acc00);  acc01 = MFMA(fa.v, b1, acc01);
      acc10 = MFMA(fb.v, b0, acc10);  acc11 = MFMA(fb.v, b1, acc11);
    }

    // D layout: row(batch) = 16*mt + 4*lk + j, col(gate) = 16*nt + ln
#pragma unroll
    for (int j = 0; j < 4; ++j) {
      red[w][(lk << 2) + j][ln]           = acc00[j];
      red[w][(lk << 2) + j][16 + ln]      = acc01[j];
      red[w][16 + (lk << 2) + j][ln]      = acc10[j];
      red[w][16 + (lk << 2) + j][16 + ln] = acc11[j];
    }
    __syncthreads();

    {  // epilogue: all 256 threads, one per (batch eb, col eq)
      float gi = 0.f, gf = 0.f, gg = 0.f, go = 0.f;
#pragma unroll
      for (int ww = 0; ww < 4; ++ww) {
        gi += red[ww][eb][eq];
        gf += red[ww][eb][8 + eq];
        gg += red[ww][eb][16 + eq];
        go += red[ww][eb][24 + eq];
      }
      gi += abias[a_t][eq];       gf += abias[a_t][8 + eq];
      gg += abias[a_t][16 + eq];  go += abias[a_t][24 + eq];
      const float si = sigf(gi), sf = sigf(gf), so = sigf(go);
      const float cn = sf * c_state + si * tanhf_fast(gg);
      const float hn = so * tanhf_fast(cn);
      c_state = cn * m_t;                      // fp32 carry

      // tagged carry-h store: pair adjacent cols via shfl, no LDS staging
      const u32 tagw = (u32)(t + 1);
      const u32 self = ((u32)f2b(hn * m_t) << 16) | tagw;
      const u32 partner = (u32)__shfl_xor((int)self, 1, 64);
      if ((eq & 1) == 0) {
        const u64 tv = ((u64)partner << 32) | (u64)self;
        __hip_atomic_store(h32 + (size_t)((t + 1) & 1) * 16384 + eb * 512 +
                               blk * 4 + (eq >> 1),
                           tv, __ATOMIC_RELAXED, __HIP_MEMORY_SCOPE_AGENT);
      }
      st[eb][eq] = f2b(hn);                    // unmasked -> hs3 (off-path)
    }
    __syncthreads();

    if (tid < 32) {  // history: 16B per batch, per-block contiguous region
      us8v v = *reinterpret_cast<const us8v*>(&st[tid][0]);
      *reinterpret_cast<us8v*>(hs3u + (size_t)blk * 32768 +
                               (size_t)(tid * 511 + t) * 2) = v;
    }
  }
}

// ---------------------------------------------------------------------------
// out = hs @ W_out^T (+bias), fused logsumexp on the logmix third.
// grid = (256 Mblk of 64 rows, 24 Nblk of 80 cols). Wave w -> rows [w*16,+16).
__global__ __launch_bounds__(256, 2) void out_gemm_k(
    const u64* __restrict__ hs3u, const unsigned short* __restrict__ wout,
    const float* __restrict__ b_out, float* __restrict__ out) {
  const int mblk = blockIdx.x, nblk = blockIdx.y;
  const int tid = threadIdx.x, lane = tid & 63, w = tid >> 6;
  const int ln = lane & 15, lk = lane >> 4;
  __shared__ alignas(16) unsigned char smraw[21760];
  unsigned short* bsm = (unsigned short*)smraw;  // [80][136] bf16 B-chunk
  float* ep = (float*)smraw;                     // [64][84] f32 epilogue tile

  const int r0 = mblk * 64 + w * 16;
  f4 acc[5];
#pragma unroll
  for (int s = 0; s < 5; ++s) acc[s] = (f4){0.f, 0.f, 0.f, 0.f};

  for (int kc = 0; kc < 8; ++kc) {  // K chunks of 128
#pragma unroll
    for (int ii = 0; ii < 5; ++ii) {           // 1280 us8 chunks exact
      int i = tid + ii * 256;
      int n = i >> 4, k16 = i & 15;
      us8v v = *reinterpret_cast<const us8v*>(
          wout + (size_t)(nblk * 80 + n) * 1024 + kc * 128 + (k16 << 3));
      *reinterpret_cast<us8v*>(bsm + n * 136 + (k16 << 3)) = v;
    }
    __syncthreads();
#pragma unroll
    for (int ks = 0; ks < 4; ++ks) {
      const int k0 = kc * 128 + ks * 32 + (lk << 3);
      s8 a = *reinterpret_cast<const s8*>(
          hs3u + (size_t)(k0 >> 3) * 32768 + (size_t)(r0 + ln) * 2);
#pragma unroll
      for (int s = 0; s < 5; ++s) {
        s8 b = LD8(bsm + (s * 16 + ln) * 136 + ks * 32 + (lk << 3));
        acc[s] = MFMA(a, b, acc[s]);
      }
    }
    __syncthreads();
  }

  const int T = nblk >> 3;  // 0 logmix, 1 mu, 2 logstd
  if (T) {
    float* base = out + (size_t)10465280 * T;
    const int lc0 = (nblk - (T << 3)) * 80;
#pragma unroll
    for (int s = 0; s < 5; ++s) {
      const int lc = lc0 + s * 16 + ln;
      const float bias = b_out[T * 640 + lc];
#pragma unroll
      for (int j = 0; j < 4; ++j) {
        const int row = r0 + (lk << 2) + j;
        if (row < 16352) base[(size_t)row * 640 + lc] = acc[s][j] + bias;
      }
    }
  } else {  // logmix: bounce through LDS, per-(row, z-group) logsumexp over 5
#pragma unroll
    for (int s = 0; s < 5; ++s) {
      const float bias = b_out[nblk * 80 + s * 16 + ln];
#pragma unroll
      for (int j = 0; j < 4; ++j)
        ep[(w * 16 + (lk << 2) + j) * 84 + s * 16 + ln] = acc[s][j] + bias;
    }
    __syncthreads();
    for (int task = tid; task < 1024; task += 256) {
      const int rr = task >> 4, grp = task & 15;
      const int row = mblk * 64 + rr;
      const float* e = ep + rr * 84 + grp * 5;
      float v0 = e[0], v1 = e[1], v2 = e[2], v3 = e[3], v4 = e[4];
      float mx = fmaxf(fmaxf(fmaxf(v0, v1), fmaxf(v2, v3)), v4);
      float ssum = expf(v0 - mx) + expf(v1 - mx) + expf(v2 - mx) +
                   expf(v3 - mx) + expf(v4 - mx);
      float lse = mx + logf(ssum);
      if (row < 16352) {
        float* o = out + (size_t)row * 640 + nblk * 80 + grp * 5;
        o[0] = v0 - lse; o[1] = v1 - lse; o[2] = v2 - lse;
        o[3] = v3 - lse; o[4] = v4 - lse;
      }
    }
  }
}

// ---------------------------------------------------------------------------
__global__ __launch_bounds__(256) void donep_k(
    const u64* __restrict__ hs3u, const unsigned short* __restrict__ wout,
    const float* __restrict__ b_out, float* __restrict__ out) {
  const int lane = threadIdx.x & 63;
  const int wv = (blockIdx.x * 256 + threadIdx.x) >> 6;  // 2048 waves
  const unsigned short* wrow = wout + (size_t)1920 * 1024 + lane * 16;
  float wl[16];
#pragma unroll
  for (int i = 0; i < 16; ++i) wl[i] = b2f(wrow[i]);
  const float bias = b_out[1920];
  for (int r = wv; r < 16352; r += 2048) {
    float d = 0.f;
#pragma unroll
    for (int j = 0; j < 2; ++j) {   // regions 2*lane+j -> cols lane*16+8j..+8
      union { u64 q2[2]; unsigned short h[8]; } u;
      const u64* pp = hs3u + (size_t)(lane * 2 + j) * 32768 + (size_t)r * 2;
      u.q2[0] = pp[0]; u.q2[1] = pp[1];
#pragma unroll
      for (int i = 0; i < 8; ++i) d += b2f(u.h[i]) * wl[j * 8 + i];
    }
#pragma unroll
    for (int off = 32; off; off >>= 1) d += __shfl_down(d, off, 64);
    if (lane == 0) out[31395840 + r] = d + bias;
  }
}

// ---------------------------------------------------------------------------
extern "C" void kernel_launch(void* const* d_in, const int* in_sizes, int n_in,
                              void* d_out, int out_size, void* d_ws, size_t ws_size,
                              hipStream_t stream) {
  const float* z       = (const float*)d_in[0];
  const int*   actions = (const int*)d_in[1];
  const int*   dones   = (const int*)d_in[2];
  const float* embed   = (const float*)d_in[3];
  const float* Wih     = (const float*)d_in[4];
  const float* Whh     = (const float*)d_in[5];
  const float* bih     = (const float*)d_in[6];
  const float* bhh     = (const float*)d_in[7];
  const float* Wout    = (const float*)d_in[8];
  const float* bout    = (const float*)d_in[9];
  float* out = (float*)d_out;

  if (ws_size < WS_END) return;  // fail visibly rather than corrupt memory

  char* ws = (char*)d_ws;
  u64* h32               = (u64*)(ws + WS_H32);
  unsigned short* wout16 = (unsigned short*)(ws + WS_WOUT);  // after lstm_k
  unsigned short* zt     = (unsigned short*)(ws + WS_ZT);
  u64* hs3u              = (u64*)(ws + WS_HS3);

  // zero BOTH h32 phases: tag 0 == valid h0; kills stale tags across replays
  hipMemsetAsync(d_ws, 0, 264192, stream);

  cvt_z_k<<<2048, 256, 0, stream>>>(z, zt);
  zero_hs_tail_k<<<32, 256, 0, stream>>>(hs3u);
  lstm_k<<<128, 256, 0, stream>>>(Whh, Wih, embed, bih, bhh, actions, dones,
                                  zt, h32, hs3u);
  cvt_wout_k<<<1921, 256, 0, stream>>>(Wout, wout16);  // reuses h32 region
  out_gemm_k<<<dim3(256, 24), 256, 0, stream>>>(hs3u, wout16, bout, out);
  donep_k<<<512, 256, 0, stream>>>(hs3u, wout16, bout, out);
}

// Round 7
// 3492.873 us; speedup vs baseline: 1.2629x; 1.2629x over previous
//
#include <hip/hip_runtime.h>
#include <hip/hip_bf16.h>

// ---------------------------------------------------------------------------
// RNNModel (MDN-RNN): embed+concat -> x_pre -> 511-step LSTM -> out GEMM ->
// logsumexp heads.
//   lstm_k: persistent 128 blocks (1/CU), each owns 8 h-cols = 32 gate rows.
//     W_hh slice bf16 in LDS (64 KB). Per step MFMA [32 x 32gates x K1152].
//     Sync protocol (R5, proven): h carried as untagged bf16 pairs in u64,
//     relaxed agent-scope 8B atomics; per-block monotonic flag stored after
//     s_waitcnt vmcnt(0) drain. R7 changes:
//       (a) gather PIPELINED: all 32 8B h-loads issued straight-line into
//           regs BEFORE any MFMA -> 1 LLC RTT instead of 8 chained RTTs
//           (the R4/R5 ~6us/step plateau was this serial chain);
//       (b) all 4 waves poll flags directly (no wave0+syncthreads release).
//     R6 lesson: never poll the bulk data (retry traffic +130MB FETCH).
//   hs3: [128 regions][16384 rows][16B] per-block contiguous; out_gemm
//     A-frag = single 16B load.
// ---------------------------------------------------------------------------

typedef float f4 __attribute__((ext_vector_type(4)));
typedef short s8 __attribute__((ext_vector_type(8)));
typedef unsigned short us8v __attribute__((ext_vector_type(8)));
typedef unsigned short us4v __attribute__((ext_vector_type(4)));
typedef unsigned long long u64;
typedef unsigned u32;

#define DEV __device__ __forceinline__

DEV unsigned short f2b(float f) {          // fp32 -> bf16 RNE
  unsigned u = __float_as_uint(f);
  return (unsigned short)((u + 0x7FFFu + ((u >> 16) & 1u)) >> 16);
}
DEV float b2f(unsigned short s) { return __uint_as_float(((unsigned)s) << 16); }

DEV f4 MFMA(s8 a, s8 b, f4 c) {
  return __builtin_amdgcn_mfma_f32_16x16x32_bf16(a, b, c, 0, 0, 0);
}
DEV s8 LD8(const unsigned short* p) { return *reinterpret_cast<const s8*>(p); }

DEV u64 AL(const u64* p) {
  return __hip_atomic_load(p, __ATOMIC_RELAXED, __HIP_MEMORY_SCOPE_AGENT);
}

DEV float sigf(float x) {   // 1/(1+e^-x) via v_exp + v_rcp (~1e-6 rel)
  float e = __builtin_amdgcn_exp2f(x * -1.44269504f);
  return __builtin_amdgcn_rcpf(1.f + e);
}
DEV float tanhf_fast(float x) {  // 1 - 2/(e^{2x}+1); saturates correctly
  float e = __builtin_amdgcn_exp2f(x * 2.88539008f);
  return 1.f - 2.f * __builtin_amdgcn_rcpf(e + 1.f);
}

// ---- workspace layout (bytes) ----
// [0,512)     128 per-block arrival flags (u32, monotonic step count)
// [2048, +131072)   h64: 2 x 32 x 256 u64 (dbl-buffered carry h, bf16 packed)
// [133120, +4MiB)   zt : 512 x 32 x 128 bf16
// [4327424, +3.75MiB) wout16
// [8261632, +32MiB) hs3: 128 regions x 16384 rows x 16B
static constexpr size_t WS_HBUF = 2048;
static constexpr size_t WS_ZT   = 133120;
static constexpr size_t WS_WOUT = 4327424;
static constexpr size_t WS_HS3  = 8261632;
static constexpr size_t WS_END  = 41816064;

// ---------------------------------------------------------------------------
__global__ void cvt_wout_k(const float* __restrict__ W, unsigned short* __restrict__ o) {
  int i = blockIdx.x * 256 + threadIdx.x;         // 491776 float4 units exact
  if (i < 491776) {
    const float4 v = reinterpret_cast<const float4*>(W)[i];
    us4v u; u[0] = f2b(v.x); u[1] = f2b(v.y); u[2] = f2b(v.z); u[3] = f2b(v.w);
    reinterpret_cast<us4v*>(o)[i] = u;
  }
}

__global__ void cvt_z_k(const float* __restrict__ z, unsigned short* __restrict__ zt) {
  int u = blockIdx.x * 256 + threadIdx.x;         // 524288 units exact
  if (u < 524288) {
    int d4 = u & 31, bt = u >> 5;
    int b = bt & 31, t = bt >> 5;
    const float4 v = reinterpret_cast<const float4*>(z)[(b * 512 + t) * 32 + d4];
    us4v uu; uu[0] = f2b(v.x); uu[1] = f2b(v.y); uu[2] = f2b(v.z); uu[3] = f2b(v.w);
    reinterpret_cast<us4v*>(zt)[u] = uu;
  }
}

__global__ void zero_hs_tail_k(u64* __restrict__ hs3u) {
  // rows 16352..16383 (32 rows x 2 u64) of all 128 regions = 8192 u64
  int i = blockIdx.x * 256 + threadIdx.x;
  if (i < 8192) {
    int reg = i >> 6, rr = (i >> 1) & 31, hf = i & 1;
    hs3u[(size_t)reg * 32768 + (size_t)(16352 + rr) * 2 + hf] = 0ull;
  }
}

// ---------------------------------------------------------------------------
// Persistent LSTM. grid=128, block=256 (4 waves). Block blk owns h cols
// [8blk,8blk+8) = 32 gate rows {type*1024 + 8blk + q}. Wave w owns K-slice
// [256w,+256) of W_hh + z-K [32w,+32). 511 steps, flag barrier.
__global__ __launch_bounds__(256, 1) void lstm_k(
    const float* __restrict__ Whh, const float* __restrict__ Wih,
    const float* __restrict__ embed, const float* __restrict__ bih,
    const float* __restrict__ bhh, const int* __restrict__ actions,
    const int* __restrict__ dones, const unsigned short* __restrict__ zt,
    u64* __restrict__ h64, u64* __restrict__ hs3u,
    unsigned* __restrict__ flags) {
  const int blk = blockIdx.x;
  const int tid = threadIdx.x;
  const int lane = tid & 63;
  const int w = tid >> 6;
  const int ln = lane & 15, lk = lane >> 4;

  __shared__ alignas(16) unsigned short whh_sw[32768];   // [kt32][nt2][64][8] 64 KB
  __shared__ alignas(16) unsigned short wz_sw[4096];     // [kz4][nt2][64][8]   8 KB
  __shared__ float abias[18][32];
  __shared__ float red[4][32][34];     // stride 34: write 2-way, read <=4-way
  __shared__ alignas(16) unsigned short st[32][8];   // unmasked h staging
  __shared__ alignas(16) unsigned short stm[32][8];  // masked h staging

  for (int i = tid; i < 32768; i += 256) {
    int j = i & 7, L = (i >> 3) & 63, nt = (i >> 9) & 1, kt = i >> 10;
    int n = nt * 16 + (L & 15);
    int grow = (n >> 3) * 1024 + blk * 8 + (n & 7);
    int k = kt * 32 + ((L >> 4) << 3) + j;
    whh_sw[i] = f2b(Whh[grow * 1024 + k]);
  }
  for (int i = tid; i < 4096; i += 256) {
    int j = i & 7, L = (i >> 3) & 63, nt = (i >> 9) & 1, kz = i >> 10;
    int n = nt * 16 + (L & 15);
    int grow = (n >> 3) * 1024 + blk * 8 + (n & 7);
    int k = kz * 32 + ((L >> 4) << 3) + j;
    wz_sw[i] = f2b(Wih[grow * 144 + k]);
  }
  for (int i = tid; i < 576; i += 256) {
    int a = i >> 5, n = i & 31;
    int grow = (n >> 3) * 1024 + blk * 8 + (n & 7);
    float s = bih[grow] + bhh[grow];
    for (int j = 0; j < 16; ++j) s += embed[a * 16 + j] * Wih[grow * 144 + 128 + j];
    abias[a][n] = s;
  }
  __syncthreads();

  const int eb = tid >> 3, eq = tid & 7;   // epilogue: thread -> (batch, col)
  float c_state = 0.f;

  for (int t = 0; t < 511; ++t) {
    const int p = t & 1;
    const u64* hb = h64 + p * 8192;          // 32 rows x 256 u64

    f4 acc00 = {0.f,0.f,0.f,0.f}, acc01 = {0.f,0.f,0.f,0.f};
    f4 acc10 = {0.f,0.f,0.f,0.f}, acc11 = {0.f,0.f,0.f,0.f};

    {  // z contribution: independent of h, issue first (overlaps poll)
      const unsigned short* zb = zt + (size_t)t * 4096;
      const int kz = w * 32 + (lk << 3);
      s8 a0 = LD8(zb + ln * 128 + kz);
      s8 a1 = LD8(zb + (ln + 16) * 128 + kz);
      s8 b0 = LD8(wz_sw + (((w << 1) + 0) * 64 + lane) * 8);
      s8 b1 = LD8(wz_sw + (((w << 1) + 1) * 64 + lane) * 8);
      acc00 = MFMA(a0, b0, acc00);  acc01 = MFMA(a0, b1, acc01);
      acc10 = MFMA(a1, b0, acc10);  acc11 = MFMA(a1, b1, acc11);
    }
    const int a_t = actions[eb * 512 + t];
    const float m_t = 1.f - (float)dones[eb * 512 + t];

    if (t) {  // ALL waves poll all 128 flags (2/lane) -- no sync release hop
      const unsigned tgt = (unsigned)t;
      for (unsigned spin = 0; spin < (1u << 20); ++spin) {
        unsigned f0 = __hip_atomic_load(flags + lane, __ATOMIC_RELAXED,
                                        __HIP_MEMORY_SCOPE_AGENT);
        unsigned f1 = __hip_atomic_load(flags + 64 + lane, __ATOMIC_RELAXED,
                                        __HIP_MEMORY_SCOPE_AGENT);
        if (__all(f0 >= tgt && f1 >= tgt)) break;
        __builtin_amdgcn_s_sleep(1);
      }
    }

    // ---- pipelined gather: issue ALL 32 8B h-loads before any MFMA ----
    const u64* rowA = hb + ln * 256;
    const u64* rowB = hb + (ln + 16) * 256;
    u64 qa[16], qb[16];
#pragma unroll
    for (int kk = 0; kk < 8; ++kk) {
      const int c = (w * 8 + kk) * 8 + (lk << 1);
      qa[2 * kk]     = AL(rowA + c);
      qa[2 * kk + 1] = AL(rowA + c + 1);
      qb[2 * kk]     = AL(rowB + c);
      qb[2 * kk + 1] = AL(rowB + c + 1);
    }
#pragma unroll
    for (int kk = 0; kk < 8; ++kk) {   // consume: LDS B-frags + 4 MFMAs each
      const int kt = w * 8 + kk;
      union { u64 q[2]; s8 v; } fa, fb;
      fa.q[0] = qa[2 * kk]; fa.q[1] = qa[2 * kk + 1];
      fb.q[0] = qb[2 * kk]; fb.q[1] = qb[2 * kk + 1];
      s8 b0 = LD8(whh_sw + (((kt << 1) + 0) * 64 + lane) * 8);
      s8 b1 = LD8(whh_sw + (((kt << 1) + 1) * 64 + lane) * 8);
      acc00 = MFMA(fa.v, b0, acc00);  acc01 = MFMA(fa.v, b1, acc01);
      acc10 = MFMA(fb.v, b0, acc10);  acc11 = MFMA(fb.v, b1, acc11);
    }

    // D layout: row(batch) = 16*mt + 4*lk + j, col(gate) = 16*nt + ln
#pragma unroll
    for (int j = 0; j < 4; ++j) {
      red[w][(lk << 2) + j][ln]           = acc00[j];
      red[w][(lk << 2) + j][16 + ln]      = acc01[j];
      red[w][16 + (lk << 2) + j][ln]      = acc10[j];
      red[w][16 + (lk << 2) + j][16 + ln] = acc11[j];
    }
    __syncthreads();

    {  // epilogue: all 256 threads, one per (batch eb, col eq)
      float gi = 0.f, gf = 0.f, gg = 0.f, go = 0.f;
#pragma unroll
      for (int ww = 0; ww < 4; ++ww) {
        gi += red[ww][eb][eq];
        gf += red[ww][eb][8 + eq];
        gg += red[ww][eb][16 + eq];
        go += red[ww][eb][24 + eq];
      }
      gi += abias[a_t][eq];       gf += abias[a_t][8 + eq];
      gg += abias[a_t][16 + eq];  go += abias[a_t][24 + eq];
      const float si = sigf(gi), sf = sigf(gf), so = sigf(go);
      const float cn = sf * c_state + si * tanhf_fast(gg);
      const float hn = so * tanhf_fast(cn);
      c_state = cn * m_t;                      // fp32 carry
      st[eb][eq]  = f2b(hn);                   // unmasked -> hs3
      stm[eb][eq] = f2b(hn * m_t);             // masked   -> carry h
    }
    __syncthreads();

    if (tid < 64) {  // carry h: 64 lanes x 8B agent atomics (one instr)
      const int bb = tid >> 1, hf = tid & 1;
      const u64 vm = reinterpret_cast<const u64*>(&stm[bb][0])[hf];
      __hip_atomic_store(h64 + (1 - p) * 8192 + bb * 256 + blk * 2 + hf, vm,
                         __ATOMIC_RELAXED, __HIP_MEMORY_SCOPE_AGENT);
      asm volatile("s_waitcnt vmcnt(0)" ::: "memory");  // drain before flag
    }
    if (tid == 0)
      __hip_atomic_store(flags + blk, (unsigned)(t + 1),
                         __ATOMIC_RELAXED, __HIP_MEMORY_SCOPE_AGENT);
    if (tid < 32) {  // history (off critical path): 16B per batch
      us8v v = *reinterpret_cast<const us8v*>(&st[tid][0]);
      *reinterpret_cast<us8v*>(hs3u + (size_t)blk * 32768 +
                               (size_t)(tid * 511 + t) * 2) = v;
    }
  }
}

// ---------------------------------------------------------------------------
// out = hs @ W_out^T (+bias), fused logsumexp on the logmix third.
// grid = (256 Mblk of 64 rows, 24 Nblk of 80 cols). Wave w -> rows [w*16,+16).
__global__ __launch_bounds__(256, 2) void out_gemm_k(
    const u64* __restrict__ hs3u, const unsigned short* __restrict__ wout,
    const float* __restrict__ b_out, float* __restrict__ out) {
  const int mblk = blockIdx.x, nblk = blockIdx.y;
  const int tid = threadIdx.x, lane = tid & 63, w = tid >> 6;
  const int ln = lane & 15, lk = lane >> 4;
  __shared__ alignas(16) unsigned char smraw[21760];
  unsigned short* bsm = (unsigned short*)smraw;  // [80][136] bf16 B-chunk
  float* ep = (float*)smraw;                     // [64][84] f32 epilogue tile

  const int r0 = mblk * 64 + w * 16;
  f4 acc[5];
#pragma unroll
  for (int s = 0; s < 5; ++s) acc[s] = (f4){0.f, 0.f, 0.f, 0.f};

  for (int kc = 0; kc < 8; ++kc) {  // K chunks of 128
#pragma unroll
    for (int ii = 0; ii < 5; ++ii) {           // 1280 us8 chunks exact
      int i = tid + ii * 256;
      int n = i >> 4, k16 = i & 15;
      us8v v = *reinterpret_cast<const us8v*>(
          wout + (size_t)(nblk * 80 + n) * 1024 + kc * 128 + (k16 << 3));
      *reinterpret_cast<us8v*>(bsm + n * 136 + (k16 << 3)) = v;
    }
    __syncthreads();
#pragma unroll
    for (int ks = 0; ks < 4; ++ks) {
      const int k0 = kc * 128 + ks * 32 + (lk << 3);
      s8 a = *reinterpret_cast<const s8*>(
          hs3u + (size_t)(k0 >> 3) * 32768 + (size_t)(r0 + ln) * 2);
#pragma unroll
      for (int s = 0; s < 5; ++s) {
        s8 b = LD8(bsm + (s * 16 + ln) * 136 + ks * 32 + (lk << 3));
        acc[s] = MFMA(a, b, acc[s]);
      }
    }
    __syncthreads();
  }

  const int T = nblk >> 3;  // 0 logmix, 1 mu, 2 logstd
  if (T) {
    float* base = out + (size_t)10465280 * T;
    const int lc0 = (nblk - (T << 3)) * 80;
#pragma unroll
    for (int s = 0; s < 5; ++s) {
      const int lc = lc0 + s * 16 + ln;
      const float bias = b_out[T * 640 + lc];
#pragma unroll
      for (int j = 0; j < 4; ++j) {
        const int row = r0 + (lk << 2) + j;
        if (row < 16352) base[(size_t)row * 640 + lc] = acc[s][j] + bias;
      }
    }
  } else {  // logmix: bounce through LDS, per-(row, z-group) logsumexp over 5
#pragma unroll
    for (int s = 0; s < 5; ++s) {
      const float bias = b_out[nblk * 80 + s * 16 + ln];
#pragma unroll
      for (int j = 0; j < 4; ++j)
        ep[(w * 16 + (lk << 2) + j) * 84 + s * 16 + ln] = acc[s][j] + bias;
    }
    __syncthreads();
    for (int task = tid; task < 1024; task += 256) {
      const int rr = task >> 4, grp = task & 15;
      const int row = mblk * 64 + rr;
      const float* e = ep + rr * 84 + grp * 5;
      float v0 = e[0], v1 = e[1], v2 = e[2], v3 = e[3], v4 = e[4];
      float mx = fmaxf(fmaxf(fmaxf(v0, v1), fmaxf(v2, v3)), v4);
      float ssum = expf(v0 - mx) + expf(v1 - mx) + expf(v2 - mx) +
                   expf(v3 - mx) + expf(v4 - mx);
      float lse = mx + logf(ssum);
      if (row < 16352) {
        float* o = out + (size_t)row * 640 + nblk * 80 + grp * 5;
        o[0] = v0 - lse; o[1] = v1 - lse; o[2] = v2 - lse;
        o[3] = v3 - lse; o[4] = v4 - lse;
      }
    }
  }
}

// ---------------------------------------------------------------------------
__global__ __launch_bounds__(256) void donep_k(
    const u64* __restrict__ hs3u, const unsigned short* __restrict__ wout,
    const float* __restrict__ b_out, float* __restrict__ out) {
  const int lane = threadIdx.x & 63;
  const int wv = (blockIdx.x * 256 + threadIdx.x) >> 6;  // 2048 waves
  const unsigned short* wrow = wout + (size_t)1920 * 1024 + lane * 16;
  float wl[16];
#pragma unroll
  for (int i = 0; i < 16; ++i) wl[i] = b2f(wrow[i]);
  const float bias = b_out[1920];
  for (int r = wv; r < 16352; r += 2048) {
    float d = 0.f;
#pragma unroll
    for (int j = 0; j < 2; ++j) {   // regions 2*lane+j -> cols lane*16+8j..+8
      union { u64 q2[2]; unsigned short h[8]; } u;
      const u64* pp = hs3u + (size_t)(lane * 2 + j) * 32768 + (size_t)r * 2;
      u.q2[0] = pp[0]; u.q2[1] = pp[1];
#pragma unroll
      for (int i = 0; i < 8; ++i) d += b2f(u.h[i]) * wl[j * 8 + i];
    }
#pragma unroll
    for (int off = 32; off; off >>= 1) d += __shfl_down(d, off, 64);
    if (lane == 0) out[31395840 + r] = d + bias;
  }
}

// ---------------------------------------------------------------------------
extern "C" void kernel_launch(void* const* d_in, const int* in_sizes, int n_in,
                              void* d_out, int out_size, void* d_ws, size_t ws_size,
                              hipStream_t stream) {
  const float* z       = (const float*)d_in[0];
  const int*   actions = (const int*)d_in[1];
  const int*   dones   = (const int*)d_in[2];
  const float* embed   = (const float*)d_in[3];
  const float* Wih     = (const float*)d_in[4];
  const float* Whh     = (const float*)d_in[5];
  const float* bih     = (const float*)d_in[6];
  const float* bhh     = (const float*)d_in[7];
  const float* Wout    = (const float*)d_in[8];
  const float* bout    = (const float*)d_in[9];
  float* out = (float*)d_out;

  if (ws_size < WS_END) return;  // fail visibly rather than corrupt memory

  char* ws = (char*)d_ws;
  unsigned* flags        = (unsigned*)(ws);
  u64* h64               = (u64*)(ws + WS_HBUF);
  unsigned short* zt     = (unsigned short*)(ws + WS_ZT);
  unsigned short* wout16 = (unsigned short*)(ws + WS_WOUT);
  u64* hs3u              = (u64*)(ws + WS_HS3);

  // zero flags + initial h (h0 = 0); must happen every launch
  hipMemsetAsync(d_ws, 0, 133120, stream);

  cvt_wout_k<<<1921, 256, 0, stream>>>(Wout, wout16);
  cvt_z_k<<<2048, 256, 0, stream>>>(z, zt);
  zero_hs_tail_k<<<32, 256, 0, stream>>>(hs3u);
  lstm_k<<<128, 256, 0, stream>>>(Whh, Wih, embed, bih, bhh, actions, dones,
                                  zt, h64, hs3u, flags);
  out_gemm_k<<<dim3(256, 24), 256, 0, stream>>>(hs3u, wout16, bout, out);
  donep_k<<<512, 256, 0, stream>>>(hs3u, wout16, bout, out);
}